// Round 14
// baseline (40.106 us; speedup 1.0000x reference)
//
#include <hip/hip_runtime.h>

#define BB   8
#define RR   128
#define SS   512
#define DD   33
#define EE   128
#define HH   4
#define EKK  32
#define NHH  128
#define HD   (HH*DD)      // 132

// ---- workspace layout (float offsets) ----
#define WS_KT   0                          // B*E*S = 524288 (transposed k-proj)
#define WS_WOT  (BB*EE*SS)                 // HD*NH = 16896

#define NB_KP   512
#define NB_WOT2 66
#define NB_PREP (NB_KP + NB_WOT2)

// ============================================================== K1: prep
// kproj only (+ Wo transpose). XCD-aware: batch = blk & 7 so kt[b] is
// written by the same XCD whose fused blocks re-read it 64x.
__global__ __launch_bounds__(256) void prep_kernel(
    const float* __restrict__ key,
    const float* __restrict__ Wk, const float* __restrict__ bk,
    const float* __restrict__ Wo, float* __restrict__ ws)
{
    __shared__ float rows[8 * EE];
    int blk = blockIdx.x, tid = threadIdx.x;

    if (blk < NB_KP) {                 // ---- k proj, 8 rows -> kt[b,e,s]
        int bb = blk & 7, j = blk >> 3;
        int s8 = bb * SS + j * 8;
#pragma unroll
        for (int i = 0; i < 4; ++i) rows[i * 256 + tid] = key[s8 * EE + i * 256 + tid];
        __syncthreads();
        int g = tid >> 7, e = tid & 127;
        float acc[4];
        float bv = bk[e];
#pragma unroll
        for (int p = 0; p < 4; ++p) acc[p] = bv;
        const float4* W4 = (const float4*)(Wk + e * EE);
        const float4* R4 = (const float4*)rows;
#pragma unroll
        for (int j4 = 0; j4 < EE / 4; ++j4) {
            float4 w = W4[j4];
#pragma unroll
            for (int p = 0; p < 4; ++p) {
                float4 rv = R4[(g * 4 + p) * 32 + j4];
                acc[p] += w.x * rv.x + w.y * rv.y + w.z * rv.z + w.w * rv.w;
            }
        }
        int s0 = j * 8;
        float4 v; v.x = acc[0]; v.y = acc[1]; v.z = acc[2]; v.w = acc[3];
        *(float4*)(ws + WS_KT + (bb * EE + e) * SS + s0 + g * 4) = v;
        return;
    }
    blk -= NB_KP;

    {                                  // ---- Wo transpose -> wot[j][n]
        int gid = blk * 256 + tid;
        if (gid < HD * NHH) {
            int n = gid & 127, j = gid >> 7;
            ws[WS_WOT + gid] = Wo[n * HD + j];
        }
    }
}

// ===== K2: qproj + sa + scores + masked softmax + PV + GEMV, 2 r/block
// XCD-aware: batch = blk & 7.
#define POOL_REDP 0        // [8][2][4][32]
#define POOL_REDW 2048
#define POOL_REDV 4096     // [8][32]
#define POOL_R32P 4352     // [8][2][4]
#define POOL_R32W 4416
#define POOL_R32V 4480     // [8]
#define EIDX(rr,h,s) (((rr)*HH+(h))*SS + (s))

__global__ __launch_bounds__(512) void fused_kernel(
    const float* __restrict__ query, const float* __restrict__ kt,
    const float* __restrict__ value, const float* __restrict__ maskp,
    const float* __restrict__ tt, const float* __restrict__ qt,
    const float* __restrict__ stridev, const float* __restrict__ Wr,
    const float* __restrict__ brv,
    const float* __restrict__ Wq, const float* __restrict__ bq,
    const float* __restrict__ wot, const float* __restrict__ bo,
    float* __restrict__ out)
{
    __shared__ float s_q[2][EE];
    __shared__ float s_tt[SS];
    __shared__ float s_sa[DD + 3];
    __shared__ float s_pool[4488];
    __shared__ float s_x[2][HD];
    __shared__ float s_part[4][NHH];

    int blk = blockIdx.x, tid = threadIdx.x;
    int b  = blk & 7;                      // XCD-aligned batch
    int r0 = (blk >> 3) * 2;

    // ---- phase 0: own-row q projection (no LDS staging; query row
    //      broadcasts through L1 across the 128 e-threads of each rr)
    s_tt[tid] = tt[b * SS + tid];
    if (tid < 256) {
        int rr = tid >> 7, e = tid & 127;
        const float4* qrow = (const float4*)(query + (b * RR + r0 + rr) * EE);
        const float4* wrow = (const float4*)(Wq + e * EE);
        float acc = bq[e];
#pragma unroll
        for (int j = 0; j < EE / 4; ++j) {
            float4 qv = qrow[j], wv = wrow[j];
            acc += qv.x * wv.x + qv.y * wv.y + qv.z * wv.z + qv.w * wv.w;
        }
        s_q[rr][e] = acc;
    } else if (tid >= 256 && tid < 256 + DD) {   // sa on wave 4 (parallel)
        int dd = tid - 256;
        float acc = brv[dd];
#pragma unroll
        for (int j = 0; j < DD; ++j) acc += stridev[j] * Wr[dd * DD + j];
        float sv = 1.0f / (1.0f + __expf(-acc));
        s_sa[dd] = sv;
        if (blk == 0) out[BB * RR * NHH + dd] = sv;  // sa output tail
    }
    __syncthreads();

    // ---- phase A: E[rr][h][s] = exp(score); float4 k loads shared by rr
    {
        int h = tid >> 7, sq = tid & 127;
        const float* kb = kt + (b * EE + h * EKK) * SS;
        float4 a0 = {0,0,0,0}, a1 = {0,0,0,0};
#pragma unroll
        for (int e = 0; e < EKK; ++e) {
            float4 kv = ((const float4*)(kb + e * SS))[sq];
            float q0 = s_q[0][h * EKK + e];
            float q1 = s_q[1][h * EKK + e];
            a0.x += q0 * kv.x; a0.y += q0 * kv.y; a0.z += q0 * kv.z; a0.w += q0 * kv.w;
            a1.x += q1 * kv.x; a1.y += q1 * kv.y; a1.z += q1 * kv.z; a1.w += q1 * kv.w;
        }
        const float scale = 0.17677669529663687f;  // 1/sqrt(32)
        float4 e0, e1;
        e0.x = __expf(a0.x * scale); e0.y = __expf(a0.y * scale);
        e0.z = __expf(a0.z * scale); e0.w = __expf(a0.w * scale);
        e1.x = __expf(a1.x * scale); e1.y = __expf(a1.y * scale);
        e1.z = __expf(a1.z * scale); e1.w = __expf(a1.w * scale);
        ((float4*)&s_pool[EIDX(0, h, 0)])[sq] = e0;
        ((float4*)&s_pool[EIDX(1, h, 0)])[sq] = e1;
    }
    __syncthreads();

    // ---- phase B: lane = (s-half, d<32); 32 consecutive s, b128 E reads
    int wv = tid >> 6, lane = tid & 63;
    int sp = lane >> 5, d = lane & 31;
    int wbase = wv * 64;
    int sb0 = wbase + sp * 32;
    float qtr0 = qt[r0], qtr1 = qt[r0 + 1];

    float ps0[HH] = {0,0,0,0}, ps1[HH] = {0,0,0,0};
    float ws0_[HH] = {0,0,0,0}, ws1_[HH] = {0,0,0,0};
    float vsum = 0.f;
    {
        float sad = s_sa[d];
        float lo0 = qtr0 - sad, hi0 = qtr0 + sad;
        float lo1 = qtr1 - sad, hi1 = qtr1 + sad;
        const float* vp = value + (size_t)(b * SS + sb0) * DD + d;
        const float* mp = maskp + (size_t)(b * SS + sb0) * DD + d;
#pragma unroll
        for (int i4 = 0; i4 < 8; ++i4) {
            int s4 = sb0 + i4 * 4;
            float4 t4 = *(const float4*)&s_tt[s4];
            float4 e0q[HH], e1q[HH];
#pragma unroll
            for (int h = 0; h < HH; ++h) {
                e0q[h] = *(const float4*)&s_pool[EIDX(0, h, s4)];
                e1q[h] = *(const float4*)&s_pool[EIDX(1, h, s4)];
            }
            float tvs[4] = {t4.x, t4.y, t4.z, t4.w};
#pragma unroll
            for (int u = 0; u < 4; ++u) {
                int i = i4 * 4 + u;
                float vv = vp[i * DD];
                float mv = mp[i * DD];
                float tv = tvs[u];
                bool mb = (mv != 0.f);
                bool k0 = mb & (tv >= lo0) & (tv <= hi0);
                bool k1 = mb & (tv >= lo1) & (tv <= hi1);
                vsum += vv;
                float g0  = k0 ? 1.f : 0.f, gv0 = k0 ? vv : 0.f;
                float g1  = k1 ? 1.f : 0.f, gv1 = k1 ? vv : 0.f;
#pragma unroll
                for (int h = 0; h < HH; ++h) {
                    float e0v = ((const float*)&e0q[h])[u];
                    float e1v = ((const float*)&e1q[h])[u];
                    ps0[h]  = fmaf(e0v, g0,  ps0[h]);
                    ws0_[h] = fmaf(e0v, gv0, ws0_[h]);
                    ps1[h]  = fmaf(e1v, g1,  ps1[h]);
                    ws1_[h] = fmaf(e1v, gv1, ws1_[h]);
                }
            }
        }
#pragma unroll
        for (int h = 0; h < HH; ++h) {
            ps0[h] += __shfl_xor(ps0[h], 32); ws0_[h] += __shfl_xor(ws0_[h], 32);
            ps1[h] += __shfl_xor(ps1[h], 32); ws1_[h] += __shfl_xor(ws1_[h], 32);
        }
        vsum += __shfl_xor(vsum, 32);
    }

    // ---- d = 32 tail: lane = trr*32 + th*8 + tj; 8 consecutive s, b128 E
    float tps = 0.f, tws = 0.f, tvs = 0.f;
    {
        int trr = lane >> 5, th = (lane >> 3) & 3, tj = lane & 7;
        float sad = s_sa[32];
        float qtrX = trr ? qtr1 : qtr0;
        float lo = qtrX - sad, hi = qtrX + sad;
        int sb = wbase + tj * 8;
        float4 ea = *(const float4*)&s_pool[EIDX(trr, th, sb)];
        float4 eb = *(const float4*)&s_pool[EIDX(trr, th, sb + 4)];
        float4 ta = *(const float4*)&s_tt[sb];
        float4 tb = *(const float4*)&s_tt[sb + 4];
        float evals[8] = {ea.x,ea.y,ea.z,ea.w,eb.x,eb.y,eb.z,eb.w};
        float tvals[8] = {ta.x,ta.y,ta.z,ta.w,tb.x,tb.y,tb.z,tb.w};
#pragma unroll
        for (int i = 0; i < 8; ++i) {
            int s = sb + i;
            float vv = value[(size_t)(b * SS + s) * DD + 32];
            float mv = maskp[(size_t)(b * SS + s) * DD + 32];
            bool k = (mv != 0.f) & (tvals[i] >= lo) & (tvals[i] <= hi);
            float p = k ? evals[i] : 0.f;
            tps += p; tws = fmaf(p, vv, tws); tvs += vv;
        }
#pragma unroll
        for (int off = 1; off < 8; off <<= 1) {
            tps += __shfl_xor(tps, off);
            tws += __shfl_xor(tws, off);
            tvs += __shfl_xor(tvs, off);
        }
    }
    __syncthreads();   // all E reads done; pool reusable

    if (lane < 32) {
#pragma unroll
        for (int h = 0; h < HH; ++h) {
            s_pool[POOL_REDP + ((wv * 2 + 0) * HH + h) * 32 + d] = ps0[h];
            s_pool[POOL_REDP + ((wv * 2 + 1) * HH + h) * 32 + d] = ps1[h];
            s_pool[POOL_REDW + ((wv * 2 + 0) * HH + h) * 32 + d] = ws0_[h];
            s_pool[POOL_REDW + ((wv * 2 + 1) * HH + h) * 32 + d] = ws1_[h];
        }
        s_pool[POOL_REDV + wv * 32 + d] = vsum;
    }
    if ((lane & 7) == 0) {
        int trr = lane >> 5, th = (lane >> 3) & 3;
        s_pool[POOL_R32P + (wv * 2 + trr) * HH + th] = tps;
        s_pool[POOL_R32W + (wv * 2 + trr) * HH + th] = tws;
        if (lane == 0) s_pool[POOL_R32V + wv] = tvs;
    }
    __syncthreads();

    // ---- assemble x
    if (tid < 256) {
        int rr = tid >> 7, hd = tid & 127, h = hd >> 5, dd = hd & 31;
        float p = 0.f, w = 0.f;
#pragma unroll
        for (int k = 0; k < 8; ++k) {
            p += s_pool[POOL_REDP + ((k * 2 + rr) * HH + h) * 32 + dd];
            w += s_pool[POOL_REDW + ((k * 2 + rr) * HH + h) * 32 + dd];
        }
        float xv;
        if (p > 0.f) xv = w / p;
        else {
            float va = 0.f;
#pragma unroll
            for (int k = 0; k < 8; ++k) va += s_pool[POOL_REDV + k * 32 + dd];
            xv = va * (1.0f / SS);
        }
        s_x[rr][h * DD + dd] = xv;
    } else if (tid < 264) {
        int t = tid - 256, rr = t >> 2, h = t & 3;
        float p = 0.f, w = 0.f;
#pragma unroll
        for (int k = 0; k < 8; ++k) {
            p += s_pool[POOL_R32P + (k * 2 + rr) * HH + h];
            w += s_pool[POOL_R32W + (k * 2 + rr) * HH + h];
        }
        float xv;
        if (p > 0.f) xv = w / p;
        else {
            float va = 0.f;
#pragma unroll
            for (int k = 0; k < 8; ++k) va += s_pool[POOL_R32V + k];
            xv = va * (1.0f / SS);
        }
        s_x[rr][h * DD + 32] = xv;
    }
    __syncthreads();

    // ---- phase C: out GEMV for both r (j split 2x66)
    {
        int g2 = tid >> 7;
        int rr = g2 >> 1, jg = g2 & 1;
        int n = tid & 127;
        float acc = 0.f;
#pragma unroll
        for (int j = 0; j < 66; ++j)
            acc += s_x[rr][jg * 66 + j] * wot[(jg * 66 + j) * NHH + n];
        s_part[g2][n] = acc;
    }
    __syncthreads();
    if (tid < 256) {
        int rr = tid >> 7, n = tid & 127;
        out[(b * RR + r0 + rr) * NHH + n] =
            bo[n] + s_part[rr * 2][n] + s_part[rr * 2 + 1][n];
    }
}

// ================================================================== launch
extern "C" void kernel_launch(void* const* d_in, const int* in_sizes, int n_in,
                              void* d_out, int out_size, void* d_ws, size_t ws_size,
                              hipStream_t stream) {
    const float* query   = (const float*)d_in[0];
    const float* key     = (const float*)d_in[1];
    const float* value   = (const float*)d_in[2];
    const float* maskp   = (const float*)d_in[3];
    const float* qt      = (const float*)d_in[4];
    const float* tt      = (const float*)d_in[5];
    const float* stridev = (const float*)d_in[6];
    const float* Wq      = (const float*)d_in[7];
    const float* bq      = (const float*)d_in[8];
    const float* Wk      = (const float*)d_in[9];
    const float* bk      = (const float*)d_in[10];
    const float* Wr      = (const float*)d_in[11];
    const float* brv     = (const float*)d_in[12];
    const float* Wo      = (const float*)d_in[13];
    const float* bo      = (const float*)d_in[14];

    float* out = (float*)d_out;               // 131072 out + 33 sa
    float* ws  = (float*)d_ws;

    prep_kernel<<<NB_PREP, 256, 0, stream>>>(key, Wk, bk, Wo, ws);
    fused_kernel<<<BB * 64, 512, 0, stream>>>(
        query, ws + WS_KT, value, maskp, tt, qt,
        stridev, Wr, brv, Wq, bq, ws + WS_WOT, bo, out);
}

// Round 15
// 35.050 us; speedup vs baseline: 1.1442x; 1.1442x over previous
//
#include <hip/hip_runtime.h>

#define BB   8
#define RR   128
#define SS   512
#define DD   33
#define EE   128
#define HH   4
#define EKK  32
#define NHH  128
#define HD   (HH*DD)      // 132

// ---- workspace layout (float offsets) ----
#define WS_KT   0                          // B*E*S = 524288 (transposed k-proj)
#define WS_WOT  (BB*EE*SS)                 // HD*NH = 16896
#define WS_QP   (WS_WOT + HD*NHH)          // B*R*E = 131072

#define NB_KP   512
#define NB_QP2  128
#define NB_WOT2 66
#define NB_PREP (NB_KP + NB_QP2 + NB_WOT2)

// ============================================================== K1: prep
// XCD-aware mapping: batch = blk & 7 so writes land on the XCD that the
// fused kernel's readers of that batch also occupy.
__global__ __launch_bounds__(256) void prep_kernel(
    const float* __restrict__ query, const float* __restrict__ key,
    const float* __restrict__ Wq, const float* __restrict__ bq,
    const float* __restrict__ Wk, const float* __restrict__ bk,
    const float* __restrict__ Wo, float* __restrict__ ws)
{
    __shared__ float rows[8 * EE];
    int blk = blockIdx.x, tid = threadIdx.x;

    if (blk < NB_KP) {                 // ---- k proj, 8 rows -> kt[b,e,s]
        int bb = blk & 7, j = blk >> 3;
        int s8 = bb * SS + j * 8;
#pragma unroll
        for (int i = 0; i < 4; ++i) rows[i * 256 + tid] = key[s8 * EE + i * 256 + tid];
        __syncthreads();
        int g = tid >> 7, e = tid & 127;
        float acc[4];
        float bv = bk[e];
#pragma unroll
        for (int p = 0; p < 4; ++p) acc[p] = bv;
        const float4* W4 = (const float4*)(Wk + e * EE);
        const float4* R4 = (const float4*)rows;
#pragma unroll
        for (int j4 = 0; j4 < EE / 4; ++j4) {
            float4 w = W4[j4];
#pragma unroll
            for (int p = 0; p < 4; ++p) {
                float4 rv = R4[(g * 4 + p) * 32 + j4];
                acc[p] += w.x * rv.x + w.y * rv.y + w.z * rv.z + w.w * rv.w;
            }
        }
        int s0 = j * 8;
        float4 v; v.x = acc[0]; v.y = acc[1]; v.z = acc[2]; v.w = acc[3];
        *(float4*)(ws + WS_KT + (bb * EE + e) * SS + s0 + g * 4) = v;
        return;
    }
    blk -= NB_KP;

    if (blk < NB_QP2) {                // ---- q proj, 8 rows -> qp[b,r,e]
        int bb = blk & 7, j = blk >> 3;
        int br0 = bb * RR + j * 8;
#pragma unroll
        for (int i = 0; i < 4; ++i) rows[i * 256 + tid] = query[br0 * EE + i * 256 + tid];
        __syncthreads();
        int g = tid >> 7, e = tid & 127;
        float acc[4];
        float bv = bq[e];
#pragma unroll
        for (int p = 0; p < 4; ++p) acc[p] = bv;
        const float4* W4 = (const float4*)(Wq + e * EE);
        const float4* R4 = (const float4*)rows;
#pragma unroll
        for (int j4 = 0; j4 < EE / 4; ++j4) {
            float4 w = W4[j4];
#pragma unroll
            for (int p = 0; p < 4; ++p) {
                float4 rv = R4[(g * 4 + p) * 32 + j4];
                acc[p] += w.x * rv.x + w.y * rv.y + w.z * rv.z + w.w * rv.w;
            }
        }
#pragma unroll
        for (int p = 0; p < 4; ++p)
            ws[WS_QP + (br0 + g * 4 + p) * EE + e] = acc[p];
        return;
    }
    blk -= NB_QP2;

    {                                  // ---- Wo transpose -> wot[j][n]
        int gid = blk * 256 + tid;
        if (gid < HD * NHH) {
            int n = gid & 127, j = gid >> 7;
            ws[WS_WOT + gid] = Wo[n * HD + j];
        }
    }
}

// ================= K2: sa + scores + masked softmax + PV + GEMV, 2 r/block
// XCD-aware: batch = blk & 7. Phase B: consecutive-s lanes -> b128 E reads.
#define POOL_REDP 0        // [8][2][4][32]
#define POOL_REDW 2048
#define POOL_REDV 4096     // [8][32]
#define POOL_R32P 4352     // [8][2][4]
#define POOL_R32W 4416
#define POOL_R32V 4480     // [8]
#define EIDX(rr,h,s) (((rr)*HH+(h))*SS + (s))

__global__ __launch_bounds__(512) void fused_kernel(
    const float* __restrict__ qp, const float* __restrict__ kt,
    const float* __restrict__ value, const float* __restrict__ maskp,
    const float* __restrict__ tt, const float* __restrict__ qt,
    const float* __restrict__ stridev, const float* __restrict__ Wr,
    const float* __restrict__ brv, const float* __restrict__ wot,
    const float* __restrict__ bo, float* __restrict__ out)
{
    __shared__ float s_q[2][EE];
    __shared__ float s_tt[SS];
    __shared__ float s_sa[DD + 3];
    __shared__ float s_pool[4488];
    __shared__ float s_x[2][HD];
    __shared__ float s_part[4][NHH];

    int blk = blockIdx.x, tid = threadIdx.x;
    int b  = blk & 7;                      // XCD-aligned batch
    int r0 = (blk >> 3) * 2;

    if (tid < 256) s_q[tid >> 7][tid & 127] =
        qp[(b * RR + r0 + (tid >> 7)) * EE + (tid & 127)];
    s_tt[tid] = tt[b * SS + tid];
    if (tid < DD) {                        // sa per-block (cheap)
        float acc = brv[tid];
#pragma unroll
        for (int j = 0; j < DD; ++j) acc += stridev[j] * Wr[tid * DD + j];
        float sv = 1.0f / (1.0f + __expf(-acc));
        s_sa[tid] = sv;
        if (blk == 0) out[BB * RR * NHH + tid] = sv;   // sa output tail
    }
    __syncthreads();

    // ---- phase A: E[rr][h][s] = exp(score); float4 k loads shared by rr
    {
        int h = tid >> 7, sq = tid & 127;
        const float* kb = kt + (b * EE + h * EKK) * SS;
        float4 a0 = {0,0,0,0}, a1 = {0,0,0,0};
#pragma unroll
        for (int e = 0; e < EKK; ++e) {
            float4 kv = ((const float4*)(kb + e * SS))[sq];
            float q0 = s_q[0][h * EKK + e];
            float q1 = s_q[1][h * EKK + e];
            a0.x += q0 * kv.x; a0.y += q0 * kv.y; a0.z += q0 * kv.z; a0.w += q0 * kv.w;
            a1.x += q1 * kv.x; a1.y += q1 * kv.y; a1.z += q1 * kv.z; a1.w += q1 * kv.w;
        }
        const float scale = 0.17677669529663687f;  // 1/sqrt(32)
        float4 e0, e1;
        e0.x = __expf(a0.x * scale); e0.y = __expf(a0.y * scale);
        e0.z = __expf(a0.z * scale); e0.w = __expf(a0.w * scale);
        e1.x = __expf(a1.x * scale); e1.y = __expf(a1.y * scale);
        e1.z = __expf(a1.z * scale); e1.w = __expf(a1.w * scale);
        ((float4*)&s_pool[EIDX(0, h, 0)])[sq] = e0;
        ((float4*)&s_pool[EIDX(1, h, 0)])[sq] = e1;
    }
    __syncthreads();

    // ---- phase B: lane = (s-half, d<32); 32 CONSECUTIVE s per lane,
    //      E read as b128 (4 s per LDS instr, wave-broadcast addresses)
    int wv = tid >> 6, lane = tid & 63;
    int sp = lane >> 5, d = lane & 31;
    int wbase = wv * 64;
    int sb0 = wbase + sp * 32;             // this lane's 32-s strip
    float qtr0 = qt[r0], qtr1 = qt[r0 + 1];

    float ps0[HH] = {0,0,0,0}, ps1[HH] = {0,0,0,0};
    float ws0_[HH] = {0,0,0,0}, ws1_[HH] = {0,0,0,0};
    float vsum = 0.f;
    {
        float sad = s_sa[d];
        float lo0 = qtr0 - sad, hi0 = qtr0 + sad;
        float lo1 = qtr1 - sad, hi1 = qtr1 + sad;
        const float* vp = value + (size_t)(b * SS + sb0) * DD + d;
        const float* mp = maskp + (size_t)(b * SS + sb0) * DD + d;
#pragma unroll
        for (int i4 = 0; i4 < 8; ++i4) {
            int s4 = sb0 + i4 * 4;
            float4 t4 = *(const float4*)&s_tt[s4];
            float4 e0q[HH], e1q[HH];
#pragma unroll
            for (int h = 0; h < HH; ++h) {
                e0q[h] = *(const float4*)&s_pool[EIDX(0, h, s4)];
                e1q[h] = *(const float4*)&s_pool[EIDX(1, h, s4)];
            }
            float tvs[4] = {t4.x, t4.y, t4.z, t4.w};
#pragma unroll
            for (int u = 0; u < 4; ++u) {
                int i = i4 * 4 + u;
                float vv = vp[i * DD];
                float mv = mp[i * DD];
                float tv = tvs[u];
                bool mb = (mv != 0.f);
                bool k0 = mb & (tv >= lo0) & (tv <= hi0);
                bool k1 = mb & (tv >= lo1) & (tv <= hi1);
                vsum += vv;
                float g0  = k0 ? 1.f : 0.f, gv0 = k0 ? vv : 0.f;
                float g1  = k1 ? 1.f : 0.f, gv1 = k1 ? vv : 0.f;
#pragma unroll
                for (int h = 0; h < HH; ++h) {
                    float e0v = ((const float*)&e0q[h])[u];
                    float e1v = ((const float*)&e1q[h])[u];
                    ps0[h]  = fmaf(e0v, g0,  ps0[h]);
                    ws0_[h] = fmaf(e0v, gv0, ws0_[h]);
                    ps1[h]  = fmaf(e1v, g1,  ps1[h]);
                    ws1_[h] = fmaf(e1v, gv1, ws1_[h]);
                }
            }
        }
#pragma unroll
        for (int h = 0; h < HH; ++h) {
            ps0[h] += __shfl_xor(ps0[h], 32); ws0_[h] += __shfl_xor(ws0_[h], 32);
            ps1[h] += __shfl_xor(ps1[h], 32); ws1_[h] += __shfl_xor(ws1_[h], 32);
        }
        vsum += __shfl_xor(vsum, 32);
    }

    // ---- d = 32 tail: lane = trr*32 + th*8 + tj; 8 consecutive s, b128 E
    float tps = 0.f, tws = 0.f, tvs = 0.f;
    {
        int trr = lane >> 5, th = (lane >> 3) & 3, tj = lane & 7;
        float sad = s_sa[32];
        float qtrX = trr ? qtr1 : qtr0;
        float lo = qtrX - sad, hi = qtrX + sad;
        int sb = wbase + tj * 8;
        float4 ea = *(const float4*)&s_pool[EIDX(trr, th, sb)];
        float4 eb = *(const float4*)&s_pool[EIDX(trr, th, sb + 4)];
        float4 ta = *(const float4*)&s_tt[sb];
        float4 tb = *(const float4*)&s_tt[sb + 4];
        float evals[8] = {ea.x,ea.y,ea.z,ea.w,eb.x,eb.y,eb.z,eb.w};
        float tvals[8] = {ta.x,ta.y,ta.z,ta.w,tb.x,tb.y,tb.z,tb.w};
#pragma unroll
        for (int i = 0; i < 8; ++i) {
            int s = sb + i;
            float vv = value[(size_t)(b * SS + s) * DD + 32];
            float mv = maskp[(size_t)(b * SS + s) * DD + 32];
            bool k = (mv != 0.f) & (tvals[i] >= lo) & (tvals[i] <= hi);
            float p = k ? evals[i] : 0.f;
            tps += p; tws = fmaf(p, vv, tws); tvs += vv;
        }
#pragma unroll
        for (int off = 1; off < 8; off <<= 1) {
            tps += __shfl_xor(tps, off);
            tws += __shfl_xor(tws, off);
            tvs += __shfl_xor(tvs, off);
        }
    }
    __syncthreads();   // all E reads done; pool reusable

    if (lane < 32) {
#pragma unroll
        for (int h = 0; h < HH; ++h) {
            s_pool[POOL_REDP + ((wv * 2 + 0) * HH + h) * 32 + d] = ps0[h];
            s_pool[POOL_REDP + ((wv * 2 + 1) * HH + h) * 32 + d] = ps1[h];
            s_pool[POOL_REDW + ((wv * 2 + 0) * HH + h) * 32 + d] = ws0_[h];
            s_pool[POOL_REDW + ((wv * 2 + 1) * HH + h) * 32 + d] = ws1_[h];
        }
        s_pool[POOL_REDV + wv * 32 + d] = vsum;
    }
    if ((lane & 7) == 0) {
        int trr = lane >> 5, th = (lane >> 3) & 3;
        s_pool[POOL_R32P + (wv * 2 + trr) * HH + th] = tps;
        s_pool[POOL_R32W + (wv * 2 + trr) * HH + th] = tws;
        if (lane == 0) s_pool[POOL_R32V + wv] = tvs;
    }
    __syncthreads();

    // ---- assemble x
    if (tid < 256) {
        int rr = tid >> 7, hd = tid & 127, h = hd >> 5, dd = hd & 31;
        float p = 0.f, w = 0.f;
#pragma unroll
        for (int k = 0; k < 8; ++k) {
            p += s_pool[POOL_REDP + ((k * 2 + rr) * HH + h) * 32 + dd];
            w += s_pool[POOL_REDW + ((k * 2 + rr) * HH + h) * 32 + dd];
        }
        float xv;
        if (p > 0.f) xv = w / p;
        else {
            float va = 0.f;
#pragma unroll
            for (int k = 0; k < 8; ++k) va += s_pool[POOL_REDV + k * 32 + dd];
            xv = va * (1.0f / SS);
        }
        s_x[rr][h * DD + dd] = xv;
    } else if (tid < 264) {
        int t = tid - 256, rr = t >> 2, h = t & 3;
        float p = 0.f, w = 0.f;
#pragma unroll
        for (int k = 0; k < 8; ++k) {
            p += s_pool[POOL_R32P + (k * 2 + rr) * HH + h];
            w += s_pool[POOL_R32W + (k * 2 + rr) * HH + h];
        }
        float xv;
        if (p > 0.f) xv = w / p;
        else {
            float va = 0.f;
#pragma unroll
            for (int k = 0; k < 8; ++k) va += s_pool[POOL_R32V + k];
            xv = va * (1.0f / SS);
        }
        s_x[rr][h * DD + 32] = xv;
    }
    __syncthreads();

    // ---- phase C: out GEMV for both r (j split 2x66)
    {
        int g2 = tid >> 7;
        int rr = g2 >> 1, jg = g2 & 1;
        int n = tid & 127;
        float acc = 0.f;
#pragma unroll
        for (int j = 0; j < 66; ++j)
            acc += s_x[rr][jg * 66 + j] * wot[(jg * 66 + j) * NHH + n];
        s_part[g2][n] = acc;
    }
    __syncthreads();
    if (tid < 256) {
        int rr = tid >> 7, n = tid & 127;
        out[(b * RR + r0 + rr) * NHH + n] =
            bo[n] + s_part[rr * 2][n] + s_part[rr * 2 + 1][n];
    }
}

// ================================================================== launch
extern "C" void kernel_launch(void* const* d_in, const int* in_sizes, int n_in,
                              void* d_out, int out_size, void* d_ws, size_t ws_size,
                              hipStream_t stream) {
    const float* query   = (const float*)d_in[0];
    const float* key     = (const float*)d_in[1];
    const float* value   = (const float*)d_in[2];
    const float* maskp   = (const float*)d_in[3];
    const float* qt      = (const float*)d_in[4];
    const float* tt      = (const float*)d_in[5];
    const float* stridev = (const float*)d_in[6];
    const float* Wq      = (const float*)d_in[7];
    const float* bq      = (const float*)d_in[8];
    const float* Wk      = (const float*)d_in[9];
    const float* bk      = (const float*)d_in[10];
    const float* Wr      = (const float*)d_in[11];
    const float* brv     = (const float*)d_in[12];
    const float* Wo      = (const float*)d_in[13];
    const float* bo      = (const float*)d_in[14];

    float* out = (float*)d_out;               // 131072 out + 33 sa
    float* ws  = (float*)d_ws;

    prep_kernel<<<NB_PREP, 256, 0, stream>>>(
        query, key, Wq, bq, Wk, bk, Wo, ws);
    fused_kernel<<<BB * 64, 512, 0, stream>>>(
        ws + WS_QP, ws + WS_KT, value, maskp, tt, qt,
        stridev, Wr, brv, ws + WS_WOT, bo, out);
}